// Round 9
// baseline (467.929 us; speedup 1.0000x reference)
//
#include <hip/hip_runtime.h>
#include <hip/hip_cooperative_groups.h>
#include <stdint.h>

namespace cg = cooperative_groups;

#define NN 2048
#define MM 2048
#define NSAMP 131072   // B*N*K

typedef float  fv4 __attribute__((ext_vector_type(4)));
typedef short  bfv8 __attribute__((ext_vector_type(8)));
typedef short  bfv4 __attribute__((ext_vector_type(4)));
typedef unsigned short u16;
typedef unsigned long long u64;

__device__ inline u16 f2bf(float x){
  unsigned u = __float_as_uint(x);
  return (u16)((u + 0x7FFFu + ((u>>16)&1u)) >> 16);
}
__device__ inline float bf2f(u16 u){ return __uint_as_float(((unsigned)u)<<16); }
// load 8 consecutive f32 and pack to bf16x8 (bit-identical to packed weights)
__device__ inline bfv8 ld8f(const float* __restrict__ p){
  fv4 a = *(const fv4*)p;
  fv4 b = *(const fv4*)(p + 4);
  bfv8 r;
  r[0]=(short)f2bf(a.x); r[1]=(short)f2bf(a.y); r[2]=(short)f2bf(a.z); r[3]=(short)f2bf(a.w);
  r[4]=(short)f2bf(b.x); r[5]=(short)f2bf(b.y); r[6]=(short)f2bf(b.z); r[7]=(short)f2bf(b.w);
  return r;
}
#define MFMA16 __builtin_amdgcn_mfma_f32_16x16x32_bf16

// ---------------------------------------------------------------------------
// q/k/v via MFMA with FUSED transpose+pack of fq/fs. Weights converted from
// f32 on the fly (ld8f). Also computes psP and zeroes the knn counter.
// ---------------------------------------------------------------------------
__global__ __launch_bounds__(256) void k_qkv(
    const float* __restrict__ fq, const float* __restrict__ fs,
    const float* __restrict__ Wq, const float* __restrict__ Wk, const float* __restrict__ Wv,
    const float* __restrict__ bq, const float* __restrict__ bk, const float* __restrict__ bv,
    const float* __restrict__ ps,
    float* __restrict__ qT, float* __restrict__ kT, float* __restrict__ vT,
    fv4* __restrict__ psP, int* __restrict__ knnCtr) {
  __shared__ u16 tile[2][32 * 136];
  int bid = blockIdx.x;            // 256
  int b = bid >> 6, p0 = (bid & 63) * 32;
  int t = threadIdx.x;
  int w = t >> 6, l = t & 63, lq = l >> 4, ln = l & 15;
  if (bid == 0 && t == 0) *knnCtr = 0;
  // ---- psP tail (prep fold-in): 8192 entries over first 32 blocks ----
  {
    int gid = bid * 256 + t;
    if (gid < 8192) { int bb = gid >> 11, m = gid & 2047;
      float x = ps[(bb*3+0)*MM + m], y = ps[(bb*3+1)*MM + m], z = ps[(bb*3+2)*MM + m];
      fv4 p; p.x = x; p.y = y; p.z = z; p.w = x*x + y*y + z*z;
      psP[gid] = p; }
  }
  {
    int cq = t >> 3, n4 = (t & 7) * 4;
    #pragma unroll
    for (int it = 0; it < 4; ++it) {
      int c = it * 32 + cq;
      fv4 vq = *(const fv4*)&fq[(b*128 + c)*2048 + p0 + n4];
      fv4 vs = *(const fv4*)&fs[(b*128 + c)*2048 + p0 + n4];
      #pragma unroll
      for (int j = 0; j < 4; ++j) {
        tile[0][(n4 + j)*136 + c] = f2bf(vq[j]);
        tile[1][(n4 + j)*136 + c] = f2bf(vs[j]);
      }
    }
  }
  bfv8 A[3][4];
  #pragma unroll
  for (int mat = 0; mat < 3; ++mat) {
    const float* W = mat == 0 ? Wq : (mat == 1 ? Wk : Wv);
    #pragma unroll
    for (int kk = 0; kk < 4; ++kk)
      A[mat][kk] = ld8f(W + (w*16 + ln)*128 + kk*32 + lq*8);
  }
  __syncthreads();
  fv4 acc[3][2];
  #pragma unroll
  for (int mat = 0; mat < 3; ++mat) {
    const u16* tl = tile[mat == 0 ? 0 : 1];
    #pragma unroll
    for (int nt = 0; nt < 2; ++nt) {
      fv4 a = {0.f,0.f,0.f,0.f};
      #pragma unroll
      for (int kk = 0; kk < 4; ++kk) {
        bfv8 bb = *(const bfv8*)&tl[(nt*16 + ln)*136 + kk*32 + lq*8];
        a = MFMA16(A[mat][kk], bb, a, 0, 0, 0);
      }
      acc[mat][nt] = a;
    }
  }
  #pragma unroll
  for (int mat = 0; mat < 3; ++mat) {
    float* dst = mat == 0 ? qT : (mat == 1 ? kT : vT);
    const float* bia = mat == 0 ? bq : (mat == 1 ? bk : bv);
    fv4 bq4 = *(const fv4*)&bia[w*16 + lq*4];
    #pragma unroll
    for (int nt = 0; nt < 2; ++nt) {
      fv4 o = acc[mat][nt] + bq4;
      *(fv4*)&dst[(b*NN + p0 + nt*16 + ln)*64 + w*16 + lq*4] = o;
    }
  }
}

// ---------------------------------------------------------------------------
// KNN v2: threshold-select + fused pos-moment accumulation + FUSED posfinal
// (last-block pattern: block that finishes 2048th reduces posPart and folds
// pos-BN into Wp1f/bp1f — identical arithmetic/order to the old k_posfinal).
// ---------------------------------------------------------------------------
__global__ __launch_bounds__(256) void k_knn(
    const float* __restrict__ pq, const fv4* __restrict__ psP,
    int* __restrict__ idxb, float* __restrict__ posPart,
    const float* __restrict__ Wp1, const float* __restrict__ bp1,
    const float* __restrict__ gp, const float* __restrict__ btp,
    float* __restrict__ Wp1f, float* __restrict__ bp1f,
    int* __restrict__ knnCtr) {
  __shared__ u64 list[4][512];      // 16 KB candidate lists (tier-3 capacity)
  __shared__ u64 win[4][16];
  __shared__ int cnt[4];
  __shared__ float sacc[4][9];      // reused as `red` in the posfinal tail
  __shared__ float stf[9];
  __shared__ int lastBlk;

  const int t = threadIdx.x, w = t >> 6, lane = t & 63;
  const int qi = blockIdx.x * 4 + w;       // grid 2048 -> 0..8191
  const int b = qi >> 11, n = qi & 2047;
  const float* pqb = pq + b * 3 * NN;
  const fv4* psb = psP + b * 2048;
  const float qx = pqb[n], qy = pqb[NN + n], qz = pqb[2 * NN + n];
  const float qq = qx * qx + qy * qy + qz * qz;

  unsigned key[32];
  unsigned bkey = 0xFFFFFFFFu; unsigned bj = 0;
  #pragma unroll
  for (int j = 0; j < 32; ++j) {
    fv4 P = psb[lane + 64*j];
    float d2 = qq + P.w - 2.f * (qx * P.x + qy * P.y + qz * P.z);
    unsigned bu = __float_as_uint(d2);
    bu = (bu & 0x80000000u) ? ~bu : (bu | 0x80000000u);
    key[j] = bu;
    if (bu < bkey) { bkey = bu; bj = (unsigned)j; }
  }
  u64 e = (((u64)bkey) << 32) | (unsigned)(lane + 64*(int)bj);

  #pragma unroll
  for (int k = 2; k <= 64; k <<= 1) {
    #pragma unroll
    for (int j = k >> 1; j > 0; j >>= 1) {
      u64 x = __shfl_xor(e, j, 64);
      u64 lo = e < x ? e : x, hi = e < x ? x : e;
      bool up = ((lane & k) == 0);
      bool takeLo = (((lane & j) == 0) == up);
      e = takeLo ? lo : hi;
    }
  }
  const u64 thr = __shfl(e, 15, 64);           // M16: 16th smallest lane-min
  const unsigned T32 = (unsigned)(thr >> 32);

  if (lane == 0) cnt[w] = 0;
  #pragma unroll
  for (int j = 0; j < 32; ++j) {
    if (key[j] <= T32) {
      int p = atomicAdd(&cnt[w], 1);
      if (p < 512) list[w][p] = (((u64)key[j]) << 32) | (unsigned)(lane + 64*j);
    }
  }
  const int C = *(volatile int*)&cnt[w];       // wave-uniform

  u64 myWin = 0;
  if (C <= 64) {
    u64 v = (lane < C) ? list[w][lane] : ~0ULL;
    #pragma unroll
    for (int k = 2; k <= 64; k <<= 1) {
      #pragma unroll
      for (int j = k >> 1; j > 0; j >>= 1) {
        u64 x = __shfl_xor(v, j, 64);
        u64 lo = v < x ? v : x, hi = v < x ? x : v;
        bool up = ((lane & k) == 0);
        bool takeLo = (((lane & j) == 0) == up);
        v = takeLo ? lo : hi;
      }
    }
    myWin = v;
  } else if (C <= 128) {
    u64 e0 = list[w][lane];
    u64 e1 = (64 + lane < C) ? list[w][64 + lane] : ~0ULL;
    #pragma unroll
    for (unsigned k = 2; k <= 128; k <<= 1) {
      #pragma unroll
      for (unsigned j = k >> 1; j > 0; j >>= 1) {
        if (j < 64) {
          u64 x0 = __shfl_xor(e0, (int)j, 64);
          u64 x1 = __shfl_xor(e1, (int)j, 64);
          bool lower = ((lane & j) == 0);
          bool up0 = (k == 128) ? true : ((lane & k) == 0);
          bool up1 = (k == 128) ? true : ((k == 64) ? false : ((lane & k) == 0));
          e0 = (lower == up0) ? (e0 < x0 ? e0 : x0) : (e0 < x0 ? x0 : e0);
          e1 = (lower == up1) ? (e1 < x1 ? e1 : x1) : (e1 < x1 ? x1 : e1);
        } else {
          u64 lo = e0 < e1 ? e0 : e1, hi = e0 < e1 ? e1 : e0;
          e0 = lo; e1 = hi;
        }
      }
    }
    myWin = e0;
  } else {
    int Cc = C > 512 ? 512 : C;
    for (int i = lane; i < 512; i += 64)
      if (i >= Cc) list[w][i] = ~0ULL;
    for (int r = 0; r < 16; ++r) {
      u64 mv = ~0ULL;
      #pragma unroll
      for (int s5 = 0; s5 < 8; ++s5) {
        u64 x = list[w][s5*64 + lane];
        mv = x < mv ? x : mv;
      }
      #pragma unroll
      for (int off = 1; off <= 32; off <<= 1) {
        u64 x = __shfl_xor(mv, off, 64);
        mv = x < mv ? x : mv;
      }
      #pragma unroll
      for (int s5 = 0; s5 < 8; ++s5)
        if (list[w][s5*64 + lane] == mv) list[w][s5*64 + lane] = ~0ULL;
      if (lane == 0) win[w][r] = mv;
    }
    if (lane < 16) myWin = win[w][lane];
  }

  if (lane < 16) {
    unsigned m = (unsigned)(myWin & 0xFFFFFFFFu);
    idxb[qi * 16 + lane] = (int)m;
    fv4 P = psb[m];
    float r0 = qx - P.x, r1 = qy - P.y, r2 = qz - P.z;
    float s[9];
    s[0] = r0; s[1] = r1; s[2] = r2;
    s[3] = r0*r0; s[4] = r0*r1; s[5] = r0*r2;
    s[6] = r1*r1; s[7] = r1*r2; s[8] = r2*r2;
    #pragma unroll
    for (int off = 1; off <= 8; off <<= 1)
      #pragma unroll
      for (int i = 0; i < 9; ++i) s[i] += __shfl_xor(s[i], off, 64);
    if (lane == 0)
      #pragma unroll
      for (int i = 0; i < 9; ++i) sacc[w][i] = s[i];
  }
  __syncthreads();
  if (t < 9) posPart[blockIdx.x * 12 + t]
      = sacc[0][t] + sacc[1][t] + sacc[2][t] + sacc[3][t];

  // ---- last-block posfinal fusion ----
  __threadfence();
  __syncthreads();
  if (t == 0) {
    int old = __hip_atomic_fetch_add(knnCtr, 1, __ATOMIC_ACQ_REL,
                                     __HIP_MEMORY_SCOPE_AGENT);
    lastBlk = (old == 2047) ? 1 : 0;
  }
  __syncthreads();
  if (lastBlk) {
    float s[9];
    #pragma unroll
    for (int i = 0; i < 9; ++i) s[i] = 0.f;
    #pragma unroll
    for (int it = 0; it < 8; ++it) {
      const float* p = posPart + (it * 256 + t) * 12;
      #pragma unroll
      for (int i = 0; i < 9; ++i)
        s[i] += __hip_atomic_load(p + i, __ATOMIC_RELAXED, __HIP_MEMORY_SCOPE_AGENT);
    }
    #pragma unroll
    for (int off = 32; off > 0; off >>= 1)
      #pragma unroll
      for (int i = 0; i < 9; ++i) s[i] += __shfl_xor(s[i], off, 64);
    if ((t & 63) == 0)
      #pragma unroll
      for (int i = 0; i < 9; ++i) sacc[t >> 6][i] = s[i];
    __syncthreads();
    if (t < 9) stf[t] = sacc[0][t] + sacc[1][t] + sacc[2][t] + sacc[3][t];
    __syncthreads();
    if (t < 64) {
      int d = t;
      const float invN = 1.f / (float)NSAMP;
      float m0 = stf[0]*invN, m1 = stf[1]*invN, m2 = stf[2]*invN;
      float C00 = stf[3]*invN - m0*m0, C01 = stf[4]*invN - m0*m1, C02 = stf[5]*invN - m0*m2;
      float C11 = stf[6]*invN - m1*m1, C12 = stf[7]*invN - m1*m2, C22 = stf[8]*invN - m2*m2;
      float w0 = Wp1[d*3], w1 = Wp1[d*3+1], w2 = Wp1[d*3+2];
      float mean = w0*m0 + w1*m1 + w2*m2 + bp1[d];
      float var = w0*w0*C00 + w1*w1*C11 + w2*w2*C22 + 2.f*(w0*w1*C01 + w0*w2*C02 + w1*w2*C12);
      float scale = gp[d] * rsqrtf(var + 1e-5f);
      Wp1f[d*3]   = scale * w0;
      Wp1f[d*3+1] = scale * w1;
      Wp1f[d*3+2] = scale * w2;
      bp1f[d] = btp[d] + scale * (bp1[d] - mean);
    }
  }
}

// ---------------------------------------------------------------------------
// y-stats: Gram via MFMA. Grid 512 (16 pts/block). Wp2 converted on the fly.
// ---------------------------------------------------------------------------
__global__ __launch_bounds__(256) void k_ystats(
    const float* __restrict__ pq, const float* __restrict__ ps,
    const float* __restrict__ qT, const float* __restrict__ kT,
    const int* __restrict__ idxb,
    const float* __restrict__ Wp1f, const float* __restrict__ bp1f,
    const float* __restrict__ Wp2, const float* __restrict__ bp2,
    float* __restrict__ Gpart, float* __restrict__ ySumPart) {
  __shared__ __align__(16) unsigned char smem[21760];
  u16*   hp   = (u16*)smem;                 // [64 s][72 i] bf16
  u16*   y2   = (u16*)(smem + 9216);        // [64 d][72 s] bf16
  float* r3   = (float*)(smem + 18432);     // 192
  float* qc   = (float*)(smem + 19200);     // 256
  int*   idxA = (int*)(smem + 20224);       // 64
  float* sWp1 = (float*)(smem + 20480);     // 192
  float* sbp1 = (float*)(smem + 21248);     // 64
  float* sbp2 = (float*)(smem + 21504);     // 64

  const int t = threadIdx.x;
  const int w = t >> 6, l = t & 63, lq = l >> 4, ln = l & 15;
  const int d0 = 16*w + lq*4;

  if (t < 192) sWp1[t] = Wp1f[t];
  if (t < 64){ sbp1[t] = bp1f[t]; sbp2[t] = bp2[t]; }

  bfv8 Ape[2];
  #pragma unroll
  for (int kk = 0; kk < 2; ++kk)
    Ape[kk] = ld8f(Wp2 + (16*w + ln)*64 + kk*32 + lq*8);

  fv4 gacc[4];
  #pragma unroll
  for (int nt = 0; nt < 4; ++nt) gacc[nt] = (fv4){0.f,0.f,0.f,0.f};
  float ys[4] = {0.f, 0.f, 0.f, 0.f};
  __syncthreads();

  for (int ch = 0; ch < 4; ++ch) {
    const int p0 = blockIdx.x * 16 + ch * 4;
    const int b  = p0 >> 11;
    const int bN = b * 2048;
    if (t < 64) idxA[t] = idxb[p0*16 + t];
    qc[t] = qT[(p0 + (t>>6))*64 + (t & 63)];
    __syncthreads();
    if (t < 192) { int c = t >> 6, s = t & 63; int n = (p0 + (s>>4)) & 2047;
      r3[c*64 + s] = pq[(b*3+c)*NN + n] - ps[(b*3+c)*MM + idxA[s]]; }
    __syncthreads();
    { int s = t >> 2, iq = t & 3;
      float r0 = r3[s], r1 = r3[64+s], r2 = r3[128+s];
      u16 tmp[16];
      #pragma unroll
      for (int e = 0; e < 16; ++e) { int i = iq*16 + e;
        float v = sbp1[i] + sWp1[i*3]*r0 + sWp1[i*3+1]*r1 + sWp1[i*3+2]*r2;
        tmp[e] = f2bf(fmaxf(v, 0.f)); }
      *(bfv8*)&hp[s*72 + iq*16]     = *(const bfv8*)&tmp[0];
      *(bfv8*)&hp[s*72 + iq*16 + 8] = *(const bfv8*)&tmp[8];
    }
    __syncthreads();
    {
      fv4 pe[4];
      #pragma unroll
      for (int nt = 0; nt < 4; ++nt) {
        fv4 acc = {0.f,0.f,0.f,0.f};
        #pragma unroll
        for (int kk = 0; kk < 2; ++kk) {
          bfv8 bb = *(const bfv8*)&hp[(nt*16 + ln)*72 + kk*32 + lq*8];
          acc = MFMA16(Ape[kk], bb, acc, 0, 0, 0);
        }
        pe[nt] = acc;
      }
      fv4 bp2q = *(const fv4*)&sbp2[d0];
      #pragma unroll
      for (int nt = 0; nt < 4; ++nt) {
        int s = nt*16 + ln;
        int mi = idxA[s];
        fv4 kg = *(const fv4*)(kT + (bN + mi)*64 + d0);
        fv4 qv = *(const fv4*)&qc[nt*64 + d0];
        fv4 yv = qv - kg + pe[nt] + bp2q;
        #pragma unroll
        for (int r = 0; r < 4; ++r) { y2[(d0 + r)*72 + s] = f2bf(yv[r]); ys[r] += yv[r]; }
      }
    }
    __syncthreads();
    #pragma unroll
    for (int kk = 0; kk < 2; ++kk) {
      bfv8 aa = *(const bfv8*)&y2[(16*w + ln)*72 + kk*32 + lq*8];
      #pragma unroll
      for (int nt = 0; nt < 4; ++nt) {
        bfv8 bb = *(const bfv8*)&y2[(nt*16 + ln)*72 + kk*32 + lq*8];
        gacc[nt] = MFMA16(aa, bb, gacc[nt], 0, 0, 0);
      }
    }
    __syncthreads();
  }
  #pragma unroll
  for (int nt = 0; nt < 4; ++nt)
    #pragma unroll
    for (int r = 0; r < 4; ++r)
      Gpart[blockIdx.x*4096 + (16*w + lq*4 + r)*64 + nt*16 + ln] = gacc[nt][r];
  #pragma unroll
  for (int off = 1; off <= 8; off <<= 1) {
    #pragma unroll
    for (int r = 0; r < 4; ++r) ys[r] += __shfl_xor(ys[r], off, 64);
  }
  if (ln == 0) {
    #pragma unroll
    for (int r = 0; r < 4; ++r) ySumPart[blockIdx.x*64 + d0 + r] = ys[r];
  }
}

// ---------------------------------------------------------------------------
// COOPERATIVE: gred (blocks 0..64) | grid.sync | attnfinal (all 256 blocks).
// Identical arithmetic to the old k_gred + k_attnfinal.
// ---------------------------------------------------------------------------
__global__ __launch_bounds__(256) void k_gredattn(
    const float* __restrict__ Gpart, const float* __restrict__ ySumPart,
    float* __restrict__ G, float* __restrict__ ySum,
    const float* __restrict__ Wa1, const float* __restrict__ ba1,
    const float* __restrict__ ga, const float* __restrict__ bta,
    u16* __restrict__ Wa1fbf, float* __restrict__ ba1f) {
  __shared__ float red[256];
  __shared__ float mu[64];
  __shared__ float sc[1];
  int bid = blockIdx.x, t = threadIdx.x;
  // ---- phase 1: reduce Gram / ySum partials ----
  if (bid < 64) {
    int tj = t & 63, st = t >> 6;
    int j = bid * 64 + tj;
    float s = 0.f;
    for (int p = st * 128; p < st * 128 + 128; ++p)
      s += Gpart[p*4096 + j];
    red[st * 64 + tj] = s;
    __syncthreads();
    if (t < 64)
      G[bid * 64 + t] = red[t] + red[64 + t] + red[128 + t] + red[192 + t];
  } else if (bid == 64) {
    int tj = t & 63, st = t >> 6;
    float s = 0.f;
    for (int p = st * 128; p < st * 128 + 128; ++p)
      s += ySumPart[p*64 + tj];
    red[st * 64 + tj] = s;
    __syncthreads();
    if (t < 64)
      ySum[t] = red[t] + red[64 + t] + red[128 + t] + red[192 + t];
  }
  cg::this_grid().sync();
  // ---- phase 2: attn-BN fold, h = bid ----
  int h = bid;
  const float invN = 1.f / (float)NSAMP;
  if (t < 64) mu[t] = ySum[t] * invN;
  __syncthreads();
  float acc = 0.f;
  #pragma unroll
  for (int e = 0; e < 16; ++e) {
    int pi = t*16 + e, i = pi >> 6, j = pi & 63;
    float cov = G[pi]*invN - mu[i]*mu[j];
    acc += Wa1[h*64 + i] * Wa1[h*64 + j] * cov;
  }
  red[t] = acc;
  __syncthreads();
  for (int s = 128; s > 0; s >>= 1) { if (t < s) red[t] += red[t + s]; __syncthreads(); }
  float var = red[0];
  __syncthreads();
  red[t] = (t < 64) ? Wa1[h*64 + t] * mu[t] : 0.f;
  __syncthreads();
  for (int s = 128; s > 0; s >>= 1) { if (t < s) red[t] += red[t + s]; __syncthreads(); }
  if (t == 0) {
    float mean  = red[0] + ba1[h];
    float scale = ga[h] * rsqrtf(var + 1e-5f);
    sc[0] = scale;
    ba1f[h] = bta[h] + scale * (ba1[h] - mean);
  }
  __syncthreads();
  if (t < 64) Wa1fbf[h*64 + t] = f2bf(sc[0] * Wa1[h*64 + t]);
}

// ---------------------------------------------------------------------------
// main fused kernel (recompute) + fused epilogue. grid 512, 16 pts/block.
// (R1-proven structure; Wp2/Wa2/We converted from f32 on the fly.)
// ---------------------------------------------------------------------------
__global__ __launch_bounds__(256) void k_main(
    const float* __restrict__ pq, const float* __restrict__ ps,
    const float* __restrict__ qT, const float* __restrict__ kT, const float* __restrict__ vT,
    const int* __restrict__ idxb,
    const float* __restrict__ Wp1f, const float* __restrict__ bp1f,
    const float* __restrict__ Wp2, const float* __restrict__ bp2,
    const u16* __restrict__ Wa1fbf, const float* __restrict__ ba1f,
    const float* __restrict__ Wa2, const float* __restrict__ ba2,
    const float* __restrict__ We, const float* __restrict__ be,
    const float* __restrict__ fq,
    u16* __restrict__ aggbf, float* __restrict__ out) {
  __shared__ __align__(16) unsigned char smem[65024];
  u16*   hp   = (u16*)smem;                    // [64 s][72 i] bf16 (aliases ha)
  u16*   ha   = (u16*)smem;                    // [64 s][264 h] bf16
  u16*   ylds = (u16*)(smem + 33792);          // [64 s][72 d] bf16 (aliases at)
  float* at   = (float*)(smem + 33792);        // [64 s][68 d] f32
  u16*   vt   = (u16*)(smem + 51200);          // [64 s][72 d] bf16
  float* r3   = (float*)(smem + 60416);        // 192
  float* qc   = (float*)(smem + 61184);        // 256
  int*   idxA = (int*)(smem + 62208);          // 64
  float* sWp1 = (float*)(smem + 62464);        // 192
  float* sbp1 = (float*)(smem + 63232);        // 64
  float* sbp2 = (float*)(smem + 63488);        // 64
  float* sba1 = (float*)(smem + 63744);        // 256
  float* sba2 = (float*)(smem + 64768);        // 64

  const int t = threadIdx.x;
  const int w = t >> 6, l = t & 63, lq = l >> 4, ln = l & 15;
  const int d0 = 16*w + lq*4;

  if (t < 192) sWp1[t] = Wp1f[t];
  if (t < 64){ sbp1[t] = bp1f[t]; sbp2[t] = bp2[t]; sba2[t] = ba2[t]; }
  sba1[t] = ba1f[t];

  bfv8 Ape[2], A1[4][2], A2[8];
  #pragma unroll
  for (int kk = 0; kk < 2; ++kk)
    Ape[kk] = ld8f(Wp2 + (16*w + ln)*64 + kk*32 + lq*8);
  #pragma unroll
  for (int mt = 0; mt < 4; ++mt)
    #pragma unroll
    for (int kk = 0; kk < 2; ++kk)
      A1[mt][kk] = *(const bfv8*)(Wa1fbf + (64*w + mt*16 + ln)*64 + kk*32 + lq*8);
  #pragma unroll
  for (int kk = 0; kk < 8; ++kk)
    A2[kk] = ld8f(Wa2 + (16*w + ln)*256 + kk*32 + lq*8);
  __syncthreads();

  for (int ch = 0; ch < 4; ++ch) {
    const int p0 = blockIdx.x * 16 + ch * 4;
    const int b  = p0 >> 11;
    const int bN = b * 2048;
    if (t < 64) idxA[t] = idxb[p0*16 + t];
    qc[t] = qT[(p0 + (t>>6))*64 + (t & 63)];
    __syncthreads();
    if (t < 192) { int c = t >> 6, s = t & 63; int n = (p0 + (s>>4)) & 2047;
      r3[c*64 + s] = pq[(b*3+c)*NN + n] - ps[(b*3+c)*MM + idxA[s]]; }
    __syncthreads();
    { int s = t >> 2, iq = t & 3;
      float r0 = r3[s], r1 = r3[64+s], r2 = r3[128+s];
      u16 tmp[16];
      #pragma unroll
      for (int e = 0; e < 16; ++e) { int i = iq*16 + e;
        float v = sbp1[i] + sWp1[i*3]*r0 + sWp1[i*3+1]*r1 + sWp1[i*3+2]*r2;
        tmp[e] = f2bf(fmaxf(v, 0.f)); }
      *(bfv8*)&hp[s*72 + iq*16]     = *(const bfv8*)&tmp[0];
      *(bfv8*)&hp[s*72 + iq*16 + 8] = *(const bfv8*)&tmp[8];
    }
    __syncthreads();
    {
      fv4 pe[4];
      #pragma unroll
      for (int nt = 0; nt < 4; ++nt) {
        fv4 acc = {0.f,0.f,0.f,0.f};
        #pragma unroll
        for (int kk = 0; kk < 2; ++kk) {
          bfv8 bb = *(const bfv8*)&hp[(nt*16 + ln)*72 + kk*32 + lq*8];
          acc = MFMA16(Ape[kk], bb, acc, 0, 0, 0);
        }
        pe[nt] = acc;
      }
      fv4 bp2q = *(const fv4*)&sbp2[d0];
      #pragma unroll
      for (int nt = 0; nt < 4; ++nt) {
        int s = nt*16 + ln;
        int mi = idxA[s];
        fv4 kg = *(const fv4*)(kT + (bN + mi)*64 + d0);
        fv4 vg = *(const fv4*)(vT + (bN + mi)*64 + d0);
        fv4 qv = *(const fv4*)&qc[nt*64 + d0];
        fv4 pv = pe[nt] + bp2q;
        fv4 yv = qv - kg + pv;
        fv4 vv = vg + pv;
        u16 yp[4], vp[4];
        #pragma unroll
        for (int r = 0; r < 4; ++r) { yp[r] = f2bf(yv[r]); vp[r] = f2bf(vv[r]); }
        *(bfv4*)&ylds[s*72 + d0] = *(const bfv4*)yp;
        *(bfv4*)&vt[s*72 + d0]   = *(const bfv4*)vp;
      }
    }
    __syncthreads();
    #pragma unroll
    for (int nt = 0; nt < 4; ++nt) {
      int s = nt*16 + ln;
      bfv8 b0 = *(const bfv8*)&ylds[s*72 + lq*8];
      bfv8 b1 = *(const bfv8*)&ylds[s*72 + 32 + lq*8];
      #pragma unroll
      for (int mt = 0; mt < 4; ++mt) {
        fv4 acc = {0.f,0.f,0.f,0.f};
        acc = MFMA16(A1[mt][0], b0, acc, 0, 0, 0);
        acc = MFMA16(A1[mt][1], b1, acc, 0, 0, 0);
        int h0 = 64*w + mt*16 + lq*4;
        fv4 bq = *(const fv4*)&sba1[h0];
        u16 hv[4];
        #pragma unroll
        for (int r = 0; r < 4; ++r) hv[r] = f2bf(fmaxf(acc[r] + bq[r], 0.f));
        *(bfv4*)&ha[s*264 + h0] = *(const bfv4*)hv;
      }
    }
    __syncthreads();
    {
      fv4 acc2[4];
      #pragma unroll
      for (int nt = 0; nt < 4; ++nt) acc2[nt] = (fv4){0.f,0.f,0.f,0.f};
      #pragma unroll
      for (int kk = 0; kk < 8; ++kk) {
        #pragma unroll
        for (int nt = 0; nt < 4; ++nt) {
          bfv8 bb = *(const bfv8*)&ha[(nt*16 + ln)*264 + kk*32 + lq*8];
          acc2[nt] = MFMA16(A2[kk], bb, acc2[nt], 0, 0, 0);
        }
      }
      fv4 ba2q = *(const fv4*)&sba2[d0];
      #pragma unroll
      for (int nt = 0; nt < 4; ++nt) {
        int s = nt*16 + ln;
        fv4 o = acc2[nt] + ba2q;
        *(fv4*)&at[s*68 + d0] = o;
      }
    }
    __syncthreads();
    {
      int dd = t & 63, pt = t >> 6;
      float a[16];
      #pragma unroll
      for (int k = 0; k < 16; ++k) a[k] = at[(pt*16 + k)*68 + dd];
      float mx = a[0];
      #pragma unroll
      for (int k = 1; k < 16; ++k) mx = fmaxf(mx, a[k]);
      float sum = 0.f, num = 0.f;
      #pragma unroll
      for (int k = 0; k < 16; ++k) {
        float e = __expf(a[k] - mx);
        sum += e;
        num += e * bf2f(vt[(pt*16 + k)*72 + dd]);
      }
      aggbf[(p0 + pt)*64 + dd] = f2bf(num / sum);
    }
    __syncthreads();
  }
  // ---- fused epilogue: out = We @ agg + be + fq for this block's 16 pts ----
  {
    const int P0 = blockIdx.x * 16;
    const int b  = P0 >> 11;
    const int n0 = P0 & 2047;
    bfv8 EA[2][2];
    #pragma unroll
    for (int mt = 0; mt < 2; ++mt)
      #pragma unroll
      for (int kk = 0; kk < 2; ++kk)
        EA[mt][kk] = ld8f(We + ((w*2 + mt)*16 + ln)*64 + kk*32 + lq*8);
    const u16* bp = aggbf + (P0 + ln)*64;
    bfv8 b0 = *(const bfv8*)(bp + lq*8);
    bfv8 b1 = *(const bfv8*)(bp + 32 + lq*8);
    fv4 eacc[2];
    #pragma unroll
    for (int mt = 0; mt < 2; ++mt) {
      fv4 a = {0.f,0.f,0.f,0.f};
      a = MFMA16(EA[mt][0], b0, a, 0, 0, 0);
      a = MFMA16(EA[mt][1], b1, a, 0, 0, 0);
      eacc[mt] = a;
    }
    #pragma unroll
    for (int mt = 0; mt < 2; ++mt) {
      int c0 = (w*2 + mt)*16 + lq*4;
      fv4 bev = *(const fv4*)&be[c0];
      #pragma unroll
      for (int r = 0; r < 4; ++r) {
        int c = c0 + r;
        int o = (b*128 + c)*2048 + n0 + ln;
        out[o] = eacc[mt][r] + bev[r] + fq[o];
      }
    }
  }
}

// ---------------------------------------------------------------------------
extern "C" void kernel_launch(void* const* d_in, const int* in_sizes, int n_in,
                              void* d_out, int out_size, void* d_ws, size_t ws_size,
                              hipStream_t stream) {
  (void)in_sizes; (void)n_in; (void)out_size; (void)ws_size;
  const float* pq  = (const float*)d_in[0];
  const float* fq  = (const float*)d_in[1];
  const float* ps  = (const float*)d_in[2];
  const float* fs  = (const float*)d_in[3];
  const float* Wq  = (const float*)d_in[4];  const float* bq  = (const float*)d_in[5];
  const float* Wk  = (const float*)d_in[6];  const float* bk  = (const float*)d_in[7];
  const float* Wv  = (const float*)d_in[8];  const float* bv  = (const float*)d_in[9];
  const float* Wp1 = (const float*)d_in[10]; const float* bp1 = (const float*)d_in[11];
  const float* gp  = (const float*)d_in[12]; const float* btp = (const float*)d_in[13];
  const float* Wp2 = (const float*)d_in[14]; const float* bp2 = (const float*)d_in[15];
  const float* Wa1 = (const float*)d_in[16]; const float* ba1 = (const float*)d_in[17];
  const float* ga  = (const float*)d_in[18]; const float* bta = (const float*)d_in[19];
  const float* Wa2 = (const float*)d_in[20]; const float* ba2 = (const float*)d_in[21];
  const float* We  = (const float*)d_in[22]; const float* be  = (const float*)d_in[23];
  float* ws = (float*)d_ws;
  float* qT    = ws;                         // 524288
  float* kT    = ws + 524288;                // 524288
  float* vT    = ws + 1048576;               // 524288
  u16*   aggbf = (u16*)(ws + 1572864);       // 262144 fl (1 MB region)
  int*   idxb  = (int*)(ws + 1835008);       // 131072
  fv4*   psP   = (fv4*)(ws + 1966080);       // 32768 fl
  float* Wp1f  = ws + 1998848;               // 192
  float* bp1f  = ws + 1999040;               // 64
  float* ba1f  = ws + 1999104;               // 256
  float* G     = ws + 1999360;               // 4096
  float* ySum  = ws + 2003456;               // 64
  float* ySumP = ws + 2003520;               // 32768 (512*64)
  u16*   Wa1fbf = (u16*)(ws + 2036288);      // 8192 fl
  float* posPart = ws + 2044480;             // 24576 (2048*12)
  float* Gpart   = ws + 2069056;             // 2097152 (512*4096)
  int*   knnCtr  = (int*)(ws + 4166208);     // 1
  float* out   = (float*)d_out;

  k_qkv<<<256, 256, 0, stream>>>(fq, fs, Wq, Wk, Wv, bq, bk, bv, ps,
                                 qT, kT, vT, psP, knnCtr);
  k_knn<<<2048, 256, 0, stream>>>(pq, psP, idxb, posPart,
                                  Wp1, bp1, gp, btp, Wp1f, bp1f, knnCtr);
  k_ystats<<<512, 256, 0, stream>>>(pq, ps, qT, kT, idxb, Wp1f, bp1f, Wp2, bp2,
                                    Gpart, ySumP);
  {
    void* args[] = { (void*)&Gpart, (void*)&ySumP, (void*)&G, (void*)&ySum,
                     (void*)&Wa1, (void*)&ba1, (void*)&ga, (void*)&bta,
                     (void*)&Wa1fbf, (void*)&ba1f };
    hipLaunchCooperativeKernel((const void*)k_gredattn, dim3(256), dim3(256),
                               args, 0, stream);
  }
  k_main<<<512, 256, 0, stream>>>(pq, ps, qT, kT, vT, idxb, Wp1f, bp1f, Wp2, bp2,
                                  Wa1fbf, ba1f, Wa2, ba2, We, be, fq, aggbf, out);
}

// Round 10
// 203.569 us; speedup vs baseline: 2.2986x; 2.2986x over previous
//
#include <hip/hip_runtime.h>
#include <stdint.h>

#define NN 2048
#define MM 2048
#define NSAMP 131072   // B*N*K

typedef float  fv4 __attribute__((ext_vector_type(4)));
typedef short  bfv8 __attribute__((ext_vector_type(8)));
typedef short  bfv4 __attribute__((ext_vector_type(4)));
typedef unsigned short u16;
typedef unsigned long long u64;

__device__ inline u16 f2bf(float x){
  unsigned u = __float_as_uint(x);
  return (u16)((u + 0x7FFFu + ((u>>16)&1u)) >> 16);
}
__device__ inline float bf2f(u16 u){ return __uint_as_float(((unsigned)u)<<16); }
// load 8 consecutive f32 and pack to bf16x8 (bit-identical to packed weights)
__device__ inline bfv8 ld8f(const float* __restrict__ p){
  fv4 a = *(const fv4*)p;
  fv4 b = *(const fv4*)(p + 4);
  bfv8 r;
  r[0]=(short)f2bf(a.x); r[1]=(short)f2bf(a.y); r[2]=(short)f2bf(a.z); r[3]=(short)f2bf(a.w);
  r[4]=(short)f2bf(b.x); r[5]=(short)f2bf(b.y); r[6]=(short)f2bf(b.z); r[7]=(short)f2bf(b.w);
  return r;
}
#define MFMA16 __builtin_amdgcn_mfma_f32_16x16x32_bf16

// ---------------------------------------------------------------------------
// FRONT: grid 2304, block-partitioned union of two INDEPENDENT workloads.
//  blocks 0..255   : q/k/v MFMA (transpose+pack fq/fs, weights ld8f'd)
//  blocks 256..2303: KNN threshold-select (reads ps directly, w=x2+y2+z2
//                    inline — no psP dependency) + pos-moment partials.
// No cross-block communication (R9 lesson: per-block device fences are a
// cache-kill on CDNA4). LDS manually unioned (17408 B).
// ---------------------------------------------------------------------------
__global__ __launch_bounds__(256) void k_front(
    const float* __restrict__ fq, const float* __restrict__ fs,
    const float* __restrict__ Wq, const float* __restrict__ Wk, const float* __restrict__ Wv,
    const float* __restrict__ bq, const float* __restrict__ bk, const float* __restrict__ bv,
    const float* __restrict__ pq, const float* __restrict__ ps,
    float* __restrict__ qT, float* __restrict__ kT, float* __restrict__ vT,
    int* __restrict__ idxb, float* __restrict__ posPart) {
  __shared__ __align__(16) unsigned char smem[17408];
  const int t = threadIdx.x;

  if (blockIdx.x < 256) {
    // ================= QKV branch =================
    u16* tile = (u16*)smem;                    // [2][32*136]
    int bid = blockIdx.x;
    int b = bid >> 6, p0 = (bid & 63) * 32;
    int w = t >> 6, l = t & 63, lq = l >> 4, ln = l & 15;
    {
      int cq = t >> 3, n4 = (t & 7) * 4;
      #pragma unroll
      for (int it = 0; it < 4; ++it) {
        int c = it * 32 + cq;
        fv4 vq = *(const fv4*)&fq[(b*128 + c)*2048 + p0 + n4];
        fv4 vs = *(const fv4*)&fs[(b*128 + c)*2048 + p0 + n4];
        #pragma unroll
        for (int j = 0; j < 4; ++j) {
          tile[0*32*136 + (n4 + j)*136 + c] = f2bf(vq[j]);
          tile[1*32*136 + (n4 + j)*136 + c] = f2bf(vs[j]);
        }
      }
    }
    bfv8 A[3][4];
    #pragma unroll
    for (int mat = 0; mat < 3; ++mat) {
      const float* W = mat == 0 ? Wq : (mat == 1 ? Wk : Wv);
      #pragma unroll
      for (int kk = 0; kk < 4; ++kk)
        A[mat][kk] = ld8f(W + (w*16 + ln)*128 + kk*32 + lq*8);
    }
    __syncthreads();
    fv4 acc[3][2];
    #pragma unroll
    for (int mat = 0; mat < 3; ++mat) {
      const u16* tl = tile + (mat == 0 ? 0 : 32*136);
      #pragma unroll
      for (int nt = 0; nt < 2; ++nt) {
        fv4 a = {0.f,0.f,0.f,0.f};
        #pragma unroll
        for (int kk = 0; kk < 4; ++kk) {
          bfv8 bb = *(const bfv8*)&tl[(nt*16 + ln)*136 + kk*32 + lq*8];
          a = MFMA16(A[mat][kk], bb, a, 0, 0, 0);
        }
        acc[mat][nt] = a;
      }
    }
    #pragma unroll
    for (int mat = 0; mat < 3; ++mat) {
      float* dst = mat == 0 ? qT : (mat == 1 ? kT : vT);
      const float* bia = mat == 0 ? bq : (mat == 1 ? bk : bv);
      fv4 bq4 = *(const fv4*)&bia[w*16 + lq*4];
      #pragma unroll
      for (int nt = 0; nt < 2; ++nt) {
        fv4 o = acc[mat][nt] + bq4;
        *(fv4*)&dst[(b*NN + p0 + nt*16 + ln)*64 + w*16 + lq*4] = o;
      }
    }
    return;
  }

  // ================= KNN branch =================
  u64*   list = (u64*)smem;                    // [4][512] = 16384 B
  u64*   win  = (u64*)(smem + 16384);          // [4][16]  = 512 B
  int*   cnt  = (int*)(smem + 16896);          // [4]
  float* sacc = (float*)(smem + 16912);        // [4][9]

  const int kbid = blockIdx.x - 256;           // 0..2047
  const int w = t >> 6, lane = t & 63;
  const int qi = kbid * 4 + w;                 // 0..8191
  const int b = qi >> 11, n = qi & 2047;
  const float* pqb = pq + b * 3 * NN;
  const float* psb = ps + b * 3 * MM;
  const float qx = pqb[n], qy = pqb[NN + n], qz = pqb[2 * NN + n];
  const float qq = qx * qx + qy * qy + qz * qz;

  unsigned key[32];
  unsigned bkey = 0xFFFFFFFFu; unsigned bj = 0;
  #pragma unroll
  for (int j = 0; j < 32; ++j) {
    int m = lane + 64*j;
    float x = psb[m], y = psb[MM + m], z = psb[2*MM + m];
    float w2 = x*x + y*y + z*z;
    float d2 = qq + w2 - 2.f * (qx * x + qy * y + qz * z);
    unsigned bu = __float_as_uint(d2);
    bu = (bu & 0x80000000u) ? ~bu : (bu | 0x80000000u);
    key[j] = bu;
    if (bu < bkey) { bkey = bu; bj = (unsigned)j; }
  }
  u64 e = (((u64)bkey) << 32) | (unsigned)(lane + 64*(int)bj);

  #pragma unroll
  for (int k = 2; k <= 64; k <<= 1) {
    #pragma unroll
    for (int j = k >> 1; j > 0; j >>= 1) {
      u64 x = __shfl_xor(e, j, 64);
      u64 lo = e < x ? e : x, hi = e < x ? x : e;
      bool up = ((lane & k) == 0);
      bool takeLo = (((lane & j) == 0) == up);
      e = takeLo ? lo : hi;
    }
  }
  const u64 thr = __shfl(e, 15, 64);           // M16: 16th smallest lane-min
  const unsigned T32 = (unsigned)(thr >> 32);

  if (lane == 0) cnt[w] = 0;
  #pragma unroll
  for (int j = 0; j < 32; ++j) {
    if (key[j] <= T32) {
      int p = atomicAdd(&cnt[w], 1);
      if (p < 512) list[w*512 + p] = (((u64)key[j]) << 32) | (unsigned)(lane + 64*j);
    }
  }
  const int C = *(volatile int*)&cnt[w];       // wave-uniform

  u64 myWin = 0;
  if (C <= 64) {
    u64 v = (lane < C) ? list[w*512 + lane] : ~0ULL;
    #pragma unroll
    for (int k = 2; k <= 64; k <<= 1) {
      #pragma unroll
      for (int j = k >> 1; j > 0; j >>= 1) {
        u64 x = __shfl_xor(v, j, 64);
        u64 lo = v < x ? v : x, hi = v < x ? x : v;
        bool up = ((lane & k) == 0);
        bool takeLo = (((lane & j) == 0) == up);
        v = takeLo ? lo : hi;
      }
    }
    myWin = v;
  } else if (C <= 128) {
    u64 e0 = list[w*512 + lane];
    u64 e1 = (64 + lane < C) ? list[w*512 + 64 + lane] : ~0ULL;
    #pragma unroll
    for (unsigned k = 2; k <= 128; k <<= 1) {
      #pragma unroll
      for (unsigned j = k >> 1; j > 0; j >>= 1) {
        if (j < 64) {
          u64 x0 = __shfl_xor(e0, (int)j, 64);
          u64 x1 = __shfl_xor(e1, (int)j, 64);
          bool lower = ((lane & j) == 0);
          bool up0 = (k == 128) ? true : ((lane & k) == 0);
          bool up1 = (k == 128) ? true : ((k == 64) ? false : ((lane & k) == 0));
          e0 = (lower == up0) ? (e0 < x0 ? e0 : x0) : (e0 < x0 ? x0 : e0);
          e1 = (lower == up1) ? (e1 < x1 ? e1 : x1) : (e1 < x1 ? x1 : e1);
        } else {
          u64 lo = e0 < e1 ? e0 : e1, hi = e0 < e1 ? e1 : e0;
          e0 = lo; e1 = hi;
        }
      }
    }
    myWin = e0;
  } else {
    int Cc = C > 512 ? 512 : C;
    for (int i = lane; i < 512; i += 64)
      if (i >= Cc) list[w*512 + i] = ~0ULL;
    for (int r = 0; r < 16; ++r) {
      u64 mv = ~0ULL;
      #pragma unroll
      for (int s5 = 0; s5 < 8; ++s5) {
        u64 x = list[w*512 + s5*64 + lane];
        mv = x < mv ? x : mv;
      }
      #pragma unroll
      for (int off = 1; off <= 32; off <<= 1) {
        u64 x = __shfl_xor(mv, off, 64);
        mv = x < mv ? x : mv;
      }
      #pragma unroll
      for (int s5 = 0; s5 < 8; ++s5)
        if (list[w*512 + s5*64 + lane] == mv) list[w*512 + s5*64 + lane] = ~0ULL;
      if (lane == 0) win[w*16 + r] = mv;
    }
    if (lane < 16) myWin = win[w*16 + lane];
  }

  if (lane < 16) {
    unsigned m = (unsigned)(myWin & 0xFFFFFFFFu);
    idxb[qi * 16 + lane] = (int)m;
    float x = psb[m], y = psb[MM + m], z = psb[2*MM + m];
    float r0 = qx - x, r1 = qy - y, r2 = qz - z;
    float s[9];
    s[0] = r0; s[1] = r1; s[2] = r2;
    s[3] = r0*r0; s[4] = r0*r1; s[5] = r0*r2;
    s[6] = r1*r1; s[7] = r1*r2; s[8] = r2*r2;
    #pragma unroll
    for (int off = 1; off <= 8; off <<= 1)
      #pragma unroll
      for (int i = 0; i < 9; ++i) s[i] += __shfl_xor(s[i], off, 64);
    if (lane == 0)
      #pragma unroll
      for (int i = 0; i < 9; ++i) sacc[w*9 + i] = s[i];
  }
  __syncthreads();
  if (t < 9) posPart[kbid * 12 + t]
      = sacc[0*9 + t] + sacc[1*9 + t] + sacc[2*9 + t] + sacc[3*9 + t];
}

// ---------------------------------------------------------------------------
// reduce pos partials (2048 records, PARALLEL) + fold pos-BN into Wp1/bp1
// ---------------------------------------------------------------------------
__global__ __launch_bounds__(256) void k_posfinal(
    const float* __restrict__ Wp1, const float* __restrict__ bp1,
    const float* __restrict__ gp, const float* __restrict__ btp,
    const float* __restrict__ posPart, float* __restrict__ Wp1f, float* __restrict__ bp1f) {
  __shared__ float red[4][9];
  __shared__ float st[9];
  int t = threadIdx.x;
  int w = t >> 6, lane = t & 63;
  float s[9];
  #pragma unroll
  for (int i = 0; i < 9; ++i) s[i] = 0.f;
  #pragma unroll
  for (int it = 0; it < 8; ++it) {
    const float* p = posPart + (it * 256 + t) * 12;
    fv4 a = *(const fv4*)p;
    fv4 b4 = *(const fv4*)(p + 4);
    float c8 = p[8];
    s[0]+=a.x; s[1]+=a.y; s[2]+=a.z; s[3]+=a.w;
    s[4]+=b4.x; s[5]+=b4.y; s[6]+=b4.z; s[7]+=b4.w;
    s[8]+=c8;
  }
  #pragma unroll
  for (int off = 32; off > 0; off >>= 1)
    #pragma unroll
    for (int i = 0; i < 9; ++i) s[i] += __shfl_xor(s[i], off, 64);
  if (lane == 0)
    #pragma unroll
    for (int i = 0; i < 9; ++i) red[w][i] = s[i];
  __syncthreads();
  if (t < 9) st[t] = red[0][t] + red[1][t] + red[2][t] + red[3][t];
  __syncthreads();
  if (t < 64) {
    int d = t;
    const float invN = 1.f / (float)NSAMP;
    float m0 = st[0]*invN, m1 = st[1]*invN, m2 = st[2]*invN;
    float C00 = st[3]*invN - m0*m0, C01 = st[4]*invN - m0*m1, C02 = st[5]*invN - m0*m2;
    float C11 = st[6]*invN - m1*m1, C12 = st[7]*invN - m1*m2, C22 = st[8]*invN - m2*m2;
    float w0 = Wp1[d*3], w1 = Wp1[d*3+1], w2 = Wp1[d*3+2];
    float mean = w0*m0 + w1*m1 + w2*m2 + bp1[d];
    float var = w0*w0*C00 + w1*w1*C11 + w2*w2*C22 + 2.f*(w0*w1*C01 + w0*w2*C02 + w1*w2*C12);
    float scale = gp[d] * rsqrtf(var + 1e-5f);
    Wp1f[d*3]   = scale * w0;
    Wp1f[d*3+1] = scale * w1;
    Wp1f[d*3+2] = scale * w2;
    bp1f[d] = btp[d] + scale * (bp1[d] - mean);
  }
}

// ---------------------------------------------------------------------------
// y-stats: Gram via MFMA. Grid 512 (16 pts/block). Wp2 converted on the fly.
// ---------------------------------------------------------------------------
__global__ __launch_bounds__(256) void k_ystats(
    const float* __restrict__ pq, const float* __restrict__ ps,
    const float* __restrict__ qT, const float* __restrict__ kT,
    const int* __restrict__ idxb,
    const float* __restrict__ Wp1f, const float* __restrict__ bp1f,
    const float* __restrict__ Wp2, const float* __restrict__ bp2,
    float* __restrict__ Gpart, float* __restrict__ ySumPart) {
  __shared__ __align__(16) unsigned char smem[21760];
  u16*   hp   = (u16*)smem;                 // [64 s][72 i] bf16
  u16*   y2   = (u16*)(smem + 9216);        // [64 d][72 s] bf16
  float* r3   = (float*)(smem + 18432);     // 192
  float* qc   = (float*)(smem + 19200);     // 256
  int*   idxA = (int*)(smem + 20224);       // 64
  float* sWp1 = (float*)(smem + 20480);     // 192
  float* sbp1 = (float*)(smem + 21248);     // 64
  float* sbp2 = (float*)(smem + 21504);     // 64

  const int t = threadIdx.x;
  const int w = t >> 6, l = t & 63, lq = l >> 4, ln = l & 15;
  const int d0 = 16*w + lq*4;

  if (t < 192) sWp1[t] = Wp1f[t];
  if (t < 64){ sbp1[t] = bp1f[t]; sbp2[t] = bp2[t]; }

  bfv8 Ape[2];
  #pragma unroll
  for (int kk = 0; kk < 2; ++kk)
    Ape[kk] = ld8f(Wp2 + (16*w + ln)*64 + kk*32 + lq*8);

  fv4 gacc[4];
  #pragma unroll
  for (int nt = 0; nt < 4; ++nt) gacc[nt] = (fv4){0.f,0.f,0.f,0.f};
  float ys[4] = {0.f, 0.f, 0.f, 0.f};
  __syncthreads();

  for (int ch = 0; ch < 4; ++ch) {
    const int p0 = blockIdx.x * 16 + ch * 4;
    const int b  = p0 >> 11;
    const int bN = b * 2048;
    if (t < 64) idxA[t] = idxb[p0*16 + t];
    qc[t] = qT[(p0 + (t>>6))*64 + (t & 63)];
    __syncthreads();
    if (t < 192) { int c = t >> 6, s = t & 63; int n = (p0 + (s>>4)) & 2047;
      r3[c*64 + s] = pq[(b*3+c)*NN + n] - ps[(b*3+c)*MM + idxA[s]]; }
    __syncthreads();
    { int s = t >> 2, iq = t & 3;
      float r0 = r3[s], r1 = r3[64+s], r2 = r3[128+s];
      u16 tmp[16];
      #pragma unroll
      for (int e = 0; e < 16; ++e) { int i = iq*16 + e;
        float v = sbp1[i] + sWp1[i*3]*r0 + sWp1[i*3+1]*r1 + sWp1[i*3+2]*r2;
        tmp[e] = f2bf(fmaxf(v, 0.f)); }
      *(bfv8*)&hp[s*72 + iq*16]     = *(const bfv8*)&tmp[0];
      *(bfv8*)&hp[s*72 + iq*16 + 8] = *(const bfv8*)&tmp[8];
    }
    __syncthreads();
    {
      fv4 pe[4];
      #pragma unroll
      for (int nt = 0; nt < 4; ++nt) {
        fv4 acc = {0.f,0.f,0.f,0.f};
        #pragma unroll
        for (int kk = 0; kk < 2; ++kk) {
          bfv8 bb = *(const bfv8*)&hp[(nt*16 + ln)*72 + kk*32 + lq*8];
          acc = MFMA16(Ape[kk], bb, acc, 0, 0, 0);
        }
        pe[nt] = acc;
      }
      fv4 bp2q = *(const fv4*)&sbp2[d0];
      #pragma unroll
      for (int nt = 0; nt < 4; ++nt) {
        int s = nt*16 + ln;
        int mi = idxA[s];
        fv4 kg = *(const fv4*)(kT + (bN + mi)*64 + d0);
        fv4 qv = *(const fv4*)&qc[nt*64 + d0];
        fv4 yv = qv - kg + pe[nt] + bp2q;
        #pragma unroll
        for (int r = 0; r < 4; ++r) { y2[(d0 + r)*72 + s] = f2bf(yv[r]); ys[r] += yv[r]; }
      }
    }
    __syncthreads();
    #pragma unroll
    for (int kk = 0; kk < 2; ++kk) {
      bfv8 aa = *(const bfv8*)&y2[(16*w + ln)*72 + kk*32 + lq*8];
      #pragma unroll
      for (int nt = 0; nt < 4; ++nt) {
        bfv8 bb = *(const bfv8*)&y2[(nt*16 + ln)*72 + kk*32 + lq*8];
        gacc[nt] = MFMA16(aa, bb, gacc[nt], 0, 0, 0);
      }
    }
    __syncthreads();
  }
  #pragma unroll
  for (int nt = 0; nt < 4; ++nt)
    #pragma unroll
    for (int r = 0; r < 4; ++r)
      Gpart[blockIdx.x*4096 + (16*w + lq*4 + r)*64 + nt*16 + ln] = gacc[nt][r];
  #pragma unroll
  for (int off = 1; off <= 8; off <<= 1) {
    #pragma unroll
    for (int r = 0; r < 4; ++r) ys[r] += __shfl_xor(ys[r], off, 64);
  }
  if (ln == 0) {
    #pragma unroll
    for (int r = 0; r < 4; ++r) ySumPart[blockIdx.x*64 + d0 + r] = ys[r];
  }
}

// ---------------------------------------------------------------------------
// reduce Gram / ySum partials — PARALLEL. grid 65.
// ---------------------------------------------------------------------------
__global__ __launch_bounds__(256) void k_gred(
    const float* __restrict__ Gpart, const float* __restrict__ ySumPart,
    float* __restrict__ G, float* __restrict__ ySum) {
  __shared__ float red[256];
  int bid = blockIdx.x, t = threadIdx.x;
  int tj = t & 63, st = t >> 6;
  if (bid < 64) {
    int j = bid * 64 + tj;
    float s = 0.f;
    for (int p = st * 128; p < st * 128 + 128; ++p)
      s += Gpart[p*4096 + j];
    red[st * 64 + tj] = s;
    __syncthreads();
    if (t < 64)
      G[bid * 64 + t] = red[t] + red[64 + t] + red[128 + t] + red[192 + t];
  } else {
    float s = 0.f;
    for (int p = st * 128; p < st * 128 + 128; ++p)
      s += ySumPart[p*64 + tj];
    red[st * 64 + tj] = s;
    __syncthreads();
    if (t < 64)
      ySum[t] = red[t] + red[64 + t] + red[128 + t] + red[192 + t];
  }
}

// ---------------------------------------------------------------------------
// fold attn-BN into Wa1/ba1; emit bf16 Wa1f
// ---------------------------------------------------------------------------
__global__ __launch_bounds__(256) void k_attnfinal(
    const float* __restrict__ Wa1, const float* __restrict__ ba1,
    const float* __restrict__ ga, const float* __restrict__ bta,
    const float* __restrict__ ySum, const float* __restrict__ G,
    u16* __restrict__ Wa1fbf, float* __restrict__ ba1f) {
  __shared__ float red[256];
  __shared__ float mu[64];
  __shared__ float sc[1];
  int h = blockIdx.x, t = threadIdx.x;
  const float invN = 1.f / (float)NSAMP;
  if (t < 64) mu[t] = ySum[t] * invN;
  __syncthreads();
  float acc = 0.f;
  #pragma unroll
  for (int e = 0; e < 16; ++e) {
    int pi = t*16 + e, i = pi >> 6, j = pi & 63;
    float cov = G[pi]*invN - mu[i]*mu[j];
    acc += Wa1[h*64 + i] * Wa1[h*64 + j] * cov;
  }
  red[t] = acc;
  __syncthreads();
  for (int s = 128; s > 0; s >>= 1) { if (t < s) red[t] += red[t + s]; __syncthreads(); }
  float var = red[0];
  __syncthreads();
  red[t] = (t < 64) ? Wa1[h*64 + t] * mu[t] : 0.f;
  __syncthreads();
  for (int s = 128; s > 0; s >>= 1) { if (t < s) red[t] += red[t + s]; __syncthreads(); }
  if (t == 0) {
    float mean  = red[0] + ba1[h];
    float scale = ga[h] * rsqrtf(var + 1e-5f);
    sc[0] = scale;
    ba1f[h] = bta[h] + scale * (ba1[h] - mean);
  }
  __syncthreads();
  if (t < 64) Wa1fbf[h*64 + t] = f2bf(sc[0] * Wa1[h*64 + t]);
}

// ---------------------------------------------------------------------------
// main fused kernel (recompute) + fused epilogue. grid 512, 16 pts/block.
// ---------------------------------------------------------------------------
__global__ __launch_bounds__(256) void k_main(
    const float* __restrict__ pq, const float* __restrict__ ps,
    const float* __restrict__ qT, const float* __restrict__ kT, const float* __restrict__ vT,
    const int* __restrict__ idxb,
    const float* __restrict__ Wp1f, const float* __restrict__ bp1f,
    const float* __restrict__ Wp2, const float* __restrict__ bp2,
    const u16* __restrict__ Wa1fbf, const float* __restrict__ ba1f,
    const float* __restrict__ Wa2, const float* __restrict__ ba2,
    const float* __restrict__ We, const float* __restrict__ be,
    const float* __restrict__ fq,
    u16* __restrict__ aggbf, float* __restrict__ out) {
  __shared__ __align__(16) unsigned char smem[65024];
  u16*   hp   = (u16*)smem;                    // [64 s][72 i] bf16 (aliases ha)
  u16*   ha   = (u16*)smem;                    // [64 s][264 h] bf16
  u16*   ylds = (u16*)(smem + 33792);          // [64 s][72 d] bf16 (aliases at)
  float* at   = (float*)(smem + 33792);        // [64 s][68 d] f32
  u16*   vt   = (u16*)(smem + 51200);          // [64 s][72 d] bf16
  float* r3   = (float*)(smem + 60416);        // 192
  float* qc   = (float*)(smem + 61184);        // 256
  int*   idxA = (int*)(smem + 62208);          // 64
  float* sWp1 = (float*)(smem + 62464);        // 192
  float* sbp1 = (float*)(smem + 63232);        // 64
  float* sbp2 = (float*)(smem + 63488);        // 64
  float* sba1 = (float*)(smem + 63744);        // 256
  float* sba2 = (float*)(smem + 64768);        // 64

  const int t = threadIdx.x;
  const int w = t >> 6, l = t & 63, lq = l >> 4, ln = l & 15;
  const int d0 = 16*w + lq*4;

  if (t < 192) sWp1[t] = Wp1f[t];
  if (t < 64){ sbp1[t] = bp1f[t]; sbp2[t] = bp2[t]; sba2[t] = ba2[t]; }
  sba1[t] = ba1f[t];

  bfv8 Ape[2], A1[4][2], A2[8];
  #pragma unroll
  for (int kk = 0; kk < 2; ++kk)
    Ape[kk] = ld8f(Wp2 + (16*w + ln)*64 + kk*32 + lq*8);
  #pragma unroll
  for (int mt = 0; mt < 4; ++mt)
    #pragma unroll
    for (int kk = 0; kk < 2; ++kk)
      A1[mt][kk] = *(const bfv8*)(Wa1fbf + (64*w + mt*16 + ln)*64 + kk*32 + lq*8);
  #pragma unroll
  for (int kk = 0; kk < 8; ++kk)
    A2[kk] = ld8f(Wa2 + (16*w + ln)*256 + kk*32 + lq*8);
  __syncthreads();

  for (int ch = 0; ch < 4; ++ch) {
    const int p0 = blockIdx.x * 16 + ch * 4;
    const int b  = p0 >> 11;
    const int bN = b * 2048;
    if (t < 64) idxA[t] = idxb[p0*16 + t];
    qc[t] = qT[(p0 + (t>>6))*64 + (t & 63)];
    __syncthreads();
    if (t < 192) { int c = t >> 6, s = t & 63; int n = (p0 + (s>>4)) & 2047;
      r3[c*64 + s] = pq[(b*3+c)*NN + n] - ps[(b*3+c)*MM + idxA[s]]; }
    __syncthreads();
    { int s = t >> 2, iq = t & 3;
      float r0 = r3[s], r1 = r3[64+s], r2 = r3[128+s];
      u16 tmp[16];
      #pragma unroll
      for (int e = 0; e < 16; ++e) { int i = iq*16 + e;
        float v = sbp1[i] + sWp1[i*3]*r0 + sWp1[i*3+1]*r1 + sWp1[i*3+2]*r2;
        tmp[e] = f2bf(fmaxf(v, 0.f)); }
      *(bfv8*)&hp[s*72 + iq*16]     = *(const bfv8*)&tmp[0];
      *(bfv8*)&hp[s*72 + iq*16 + 8] = *(const bfv8*)&tmp[8];
    }
    __syncthreads();
    {
      fv4 pe[4];
      #pragma unroll
      for (int nt = 0; nt < 4; ++nt) {
        fv4 acc = {0.f,0.f,0.f,0.f};
        #pragma unroll
        for (int kk = 0; kk < 2; ++kk) {
          bfv8 bb = *(const bfv8*)&hp[(nt*16 + ln)*72 + kk*32 + lq*8];
          acc = MFMA16(Ape[kk], bb, acc, 0, 0, 0);
        }
        pe[nt] = acc;
      }
      fv4 bp2q = *(const fv4*)&sbp2[d0];
      #pragma unroll
      for (int nt = 0; nt < 4; ++nt) {
        int s = nt*16 + ln;
        int mi = idxA[s];
        fv4 kg = *(const fv4*)(kT + (bN + mi)*64 + d0);
        fv4 vg = *(const fv4*)(vT + (bN + mi)*64 + d0);
        fv4 qv = *(const fv4*)&qc[nt*64 + d0];
        fv4 pv = pe[nt] + bp2q;
        fv4 yv = qv - kg + pv;
        fv4 vv = vg + pv;
        u16 yp[4], vp[4];
        #pragma unroll
        for (int r = 0; r < 4; ++r) { yp[r] = f2bf(yv[r]); vp[r] = f2bf(vv[r]); }
        *(bfv4*)&ylds[s*72 + d0] = *(const bfv4*)yp;
        *(bfv4*)&vt[s*72 + d0]   = *(const bfv4*)vp;
      }
    }
    __syncthreads();
    #pragma unroll
    for (int nt = 0; nt < 4; ++nt) {
      int s = nt*16 + ln;
      bfv8 b0 = *(const bfv8*)&ylds[s*72 + lq*8];
      bfv8 b1 = *(const bfv8*)&ylds[s*72 + 32 + lq*8];
      #pragma unroll
      for (int mt = 0; mt < 4; ++mt) {
        fv4 acc = {0.f,0.f,0.f,0.f};
        acc = MFMA16(A1[mt][0], b0, acc, 0, 0, 0);
        acc = MFMA16(A1[mt][1], b1, acc, 0, 0, 0);
        int h0 = 64*w + mt*16 + lq*4;
        fv4 bq = *(const fv4*)&sba1[h0];
        u16 hv[4];
        #pragma unroll
        for (int r = 0; r < 4; ++r) hv[r] = f2bf(fmaxf(acc[r] + bq[r], 0.f));
        *(bfv4*)&ha[s*264 + h0] = *(const bfv4*)hv;
      }
    }
    __syncthreads();
    {
      fv4 acc2[4];
      #pragma unroll
      for (int nt = 0; nt < 4; ++nt) acc2[nt] = (fv4){0.f,0.f,0.f,0.f};
      #pragma unroll
      for (int kk = 0; kk < 8; ++kk) {
        #pragma unroll
        for (int nt = 0; nt < 4; ++nt) {
          bfv8 bb = *(const bfv8*)&ha[(nt*16 + ln)*264 + kk*32 + lq*8];
          acc2[nt] = MFMA16(A2[kk], bb, acc2[nt], 0, 0, 0);
        }
      }
      fv4 ba2q = *(const fv4*)&sba2[d0];
      #pragma unroll
      for (int nt = 0; nt < 4; ++nt) {
        int s = nt*16 + ln;
        fv4 o = acc2[nt] + ba2q;
        *(fv4*)&at[s*68 + d0] = o;
      }
    }
    __syncthreads();
    {
      int dd = t & 63, pt = t >> 6;
      float a[16];
      #pragma unroll
      for (int k = 0; k < 16; ++k) a[k] = at[(pt*16 + k)*68 + dd];
      float mx = a[0];
      #pragma unroll
      for (int k = 1; k < 16; ++k) mx = fmaxf(mx, a[k]);
      float sum = 0.f, num = 0.f;
      #pragma unroll
      for (int k = 0; k < 16; ++k) {
        float e = __expf(a[k] - mx);
        sum += e;
        num += e * bf2f(vt[(pt*16 + k)*72 + dd]);
      }
      aggbf[(p0 + pt)*64 + dd] = f2bf(num / sum);
    }
    __syncthreads();
  }
  // ---- fused epilogue: out = We @ agg + be + fq for this block's 16 pts ----
  {
    const int P0 = blockIdx.x * 16;
    const int b  = P0 >> 11;
    const int n0 = P0 & 2047;
    bfv8 EA[2][2];
    #pragma unroll
    for (int mt = 0; mt < 2; ++mt)
      #pragma unroll
      for (int kk = 0; kk < 2; ++kk)
        EA[mt][kk] = ld8f(We + ((w*2 + mt)*16 + ln)*64 + kk*32 + lq*8);
    const u16* bp = aggbf + (P0 + ln)*64;
    bfv8 b0 = *(const bfv8*)(bp + lq*8);
    bfv8 b1 = *(const bfv8*)(bp + 32 + lq*8);
    fv4 eacc[2];
    #pragma unroll
    for (int mt = 0; mt < 2; ++mt) {
      fv4 a = {0.f,0.f,0.f,0.f};
      a = MFMA16(EA[mt][0], b0, a, 0, 0, 0);
      a = MFMA16(EA[mt][1], b1, a, 0, 0, 0);
      eacc[mt] = a;
    }
    #pragma unroll
    for (int mt = 0; mt < 2; ++mt) {
      int c0 = (w*2 + mt)*16 + lq*4;
      fv4 bev = *(const fv4*)&be[c0];
      #pragma unroll
      for (int r = 0; r < 4; ++r) {
        int c = c0 + r;
        int o = (b*128 + c)*2048 + n0 + ln;
        out[o] = eacc[mt][r] + bev[r] + fq[o];
      }
    }
  }
}

// ---------------------------------------------------------------------------
extern "C" void kernel_launch(void* const* d_in, const int* in_sizes, int n_in,
                              void* d_out, int out_size, void* d_ws, size_t ws_size,
                              hipStream_t stream) {
  (void)in_sizes; (void)n_in; (void)out_size; (void)ws_size;
  const float* pq  = (const float*)d_in[0];
  const float* fq  = (const float*)d_in[1];
  const float* ps  = (const float*)d_in[2];
  const float* fs  = (const float*)d_in[3];
  const float* Wq  = (const float*)d_in[4];  const float* bq  = (const float*)d_in[5];
  const float* Wk  = (const float*)d_in[6];  const float* bk  = (const float*)d_in[7];
  const float* Wv  = (const float*)d_in[8];  const float* bv  = (const float*)d_in[9];
  const float* Wp1 = (const float*)d_in[10]; const float* bp1 = (const float*)d_in[11];
  const float* gp  = (const float*)d_in[12]; const float* btp = (const float*)d_in[13];
  const float* Wp2 = (const float*)d_in[14]; const float* bp2 = (const float*)d_in[15];
  const float* Wa1 = (const float*)d_in[16]; const float* ba1 = (const float*)d_in[17];
  const float* ga  = (const float*)d_in[18]; const float* bta = (const float*)d_in[19];
  const float* Wa2 = (const float*)d_in[20]; const float* ba2 = (const float*)d_in[21];
  const float* We  = (const float*)d_in[22]; const float* be  = (const float*)d_in[23];
  float* ws = (float*)d_ws;
  float* qT    = ws;                         // 524288
  float* kT    = ws + 524288;                // 524288
  float* vT    = ws + 1048576;               // 524288
  u16*   aggbf = (u16*)(ws + 1572864);       // 262144 fl (1 MB region)
  int*   idxb  = (int*)(ws + 1835008);       // 131072
  float* Wp1f  = ws + 1998848;               // 192
  float* bp1f  = ws + 1999040;               // 64
  float* ba1f  = ws + 1999104;               // 256
  float* G     = ws + 1999360;               // 4096
  float* ySum  = ws + 2003456;               // 64
  float* ySumP = ws + 2003520;               // 32768 (512*64)
  u16*   Wa1fbf = (u16*)(ws + 2036288);      // 8192 fl
  float* posPart = ws + 2044480;             // 24576 (2048*12)
  float* Gpart   = ws + 2069056;             // 2097152 (512*4096)
  float* out   = (float*)d_out;

  k_front<<<2304, 256, 0, stream>>>(fq, fs, Wq, Wk, Wv, bq, bk, bv, pq, ps,
                                    qT, kT, vT, idxb, posPart);
  k_posfinal<<<1, 256, 0, stream>>>(Wp1, bp1, gp, btp, posPart, Wp1f, bp1f);
  k_ystats<<<512, 256, 0, stream>>>(pq, ps, qT, kT, idxb, Wp1f, bp1f, Wp2, bp2,
                                    Gpart, ySumP);
  k_gred<<<65, 256, 0, stream>>>(Gpart, ySumP, G, ySum);
  k_attnfinal<<<256, 256, 0, stream>>>(Wa1, ba1, ga, bta, ySum, G, Wa1fbf, ba1f);
  k_main<<<512, 256, 0, stream>>>(pq, ps, qT, kT, vT, idxb, Wp1f, bp1f, Wp2, bp2,
                                  Wa1fbf, ba1f, Wa2, ba2, We, be, fq, aggbf, out);
}